// Round 4
// baseline (135.157 us; speedup 1.0000x reference)
//
#include <hip/hip_runtime.h>

#define NUM_ENT 7
#define DIM_ENT 4
#define H 128            // NEMBED_HALF
#define OUTC (2 * H)     // 256 columns per entity
#define BPB 32           // batch elements per block (R9: was 16)

typedef float f32x4 __attribute__((ext_vector_type(4)));   // native clang vector

// R9: 16-columns-per-thread layout. 8 threads per batch element (sub=tid&7),
// each owning quads {c0, c0+32, c0+64, c0+96} (c0=sub*4) in BOTH the prop
// (cols 0..127) and rel (cols 128..255) halves. Grid = B/32 = 512 blocks
// x 256 threads. Rationale: R8 (4->8 cols/thread) bought 11 us by cutting
// cross-lane-redundant diff+sqrt work; this halves it again (42 pairs'
// diffs computed by 8 lanes instead of 16) — per-elem issued ops 14.8k ->
// 12.1k (-18%). ReLU via __builtin_elementwise_max to let the backend pick
// packed v_pk_max_f32 / v_pk_add_f32 next to packed FMAs.
// VGPR ~160-170 (wr[5][4] = 80 regs of weights); grid 2 blocks/CU.
//
// Store coalescing: per store instr an 8-lane group (one batch elem) writes
// 8 x 16 B at stride 16 B = 128 B contiguous (one full line); 8 groups per
// wave hit 8 distinct elems' lines. All stores are full-line — no RMW fetch.
__global__ __launch_bounds__(256) void ace_kernel(
    const float* __restrict__ ctx,     // [28, B]
    const float* __restrict__ w_prop,  // [4, 128]
    const float* __restrict__ b_prop,  // [128]
    const float* __restrict__ w_rel,   // [5, 128]
    const float* __restrict__ b_rel,   // [128]
    float* __restrict__ out,           // [B, 7, 256]
    int B)
{
    __shared__ float s_ents[BPB][NUM_ENT * DIM_ENT];          // 32 x 28 floats

    const int tid = threadIdx.x;
    const int b0 = blockIdx.x * BPB;

    // Stage ents, bb-fastest for coalescing: t -> (k = t>>5, bb = t&31).
    // 896 elems over 256 threads -> 4 iterations (last half-masked).
#pragma unroll
    for (int t = tid; t < BPB * NUM_ENT * DIM_ENT; t += 256) {
        const int k  = t >> 5;
        const int bb = t & 31;
        s_ents[bb][k] = ctx[(size_t)k * B + (b0 + bb)];
    }
    __syncthreads();

    const int sub = tid & 7;           // column-group within batch elem (0..7)
    const int bb  = tid >> 3;          // batch elem within block (0..31)
    const int c0  = sub << 2;          // quads at c0 + {0,32,64,96}
    float* outb = out + (size_t)(b0 + bb) * (NUM_ENT * OUTC);

    const f32x4 vzero = {0.f, 0.f, 0.f, 0.f};

    // 7 entities -> registers. Rows at 112-B stride: the 8 bb-groups in a
    // wave start at banks (28*bb mod 32) = {0,28,24,20,16,12,8,4} — disjoint
    // 4-bank windows, conflict-free b128; 8 lanes/group broadcast (free).
    f32x4 e[NUM_ENT];
#pragma unroll
    for (int n = 0; n < NUM_ENT; ++n)
        e[n] = *(const f32x4*)(&s_ents[bb][n * DIM_ENT]);

    {   // ---- prop_emb: relu(ents @ w_prop + b_prop) -> cols c0 + q*32
        f32x4 wp[DIM_ENT][4], bp[4];
#pragma unroll
        for (int f = 0; f < DIM_ENT; ++f)
#pragma unroll
            for (int q = 0; q < 4; ++q)
                wp[f][q] = *(const f32x4*)(w_prop + f * H + c0 + q * 32);
#pragma unroll
        for (int q = 0; q < 4; ++q)
            bp[q] = *(const f32x4*)(b_prop + c0 + q * 32);

#pragma unroll
        for (int n = 0; n < NUM_ENT; ++n) {
            const float e0 = e[n].x, e1 = e[n].y, e2 = e[n].z, e3 = e[n].w;
#pragma unroll
            for (int q = 0; q < 4; ++q) {
                f32x4 a = bp[q];
                a += e0 * wp[0][q];
                a += e1 * wp[1][q];
                a += e2 * wp[2][q];
                a += e3 * wp[3][q];
                a = __builtin_elementwise_max(a, vzero);
                *(f32x4*)(outb + n * OUTC + c0 + q * 32) = a;
            }
        }
    }

    {   // ---- rel_emb: sum_{j!=i} relu(feat(i,j) @ w_rel + b_rel)
        //      -> cols 128 + c0 + q*32
        f32x4 wr[DIM_ENT + 1][4], br[4];
#pragma unroll
        for (int f = 0; f < DIM_ENT + 1; ++f)
#pragma unroll
            for (int q = 0; q < 4; ++q)
                wr[f][q] = *(const f32x4*)(w_rel + f * H + c0 + q * 32);
#pragma unroll
        for (int q = 0; q < 4; ++q)
            br[q] = *(const f32x4*)(b_rel + c0 + q * 32);

#pragma unroll
        for (int i = 0; i < NUM_ENT; ++i) {
            f32x4 acc[4] = {vzero, vzero, vzero, vzero};
#pragma unroll
            for (int j = 0; j < NUM_ENT; ++j) {
                if (j == i) continue;
                const float dx = e[i].x - e[j].x;
                const float dy = e[i].y - e[j].y;
                const float dz = e[i].z - e[j].z;
                const float dv = e[i].w - e[j].w;
                const float d  = __builtin_amdgcn_sqrtf(dx * dx + dy * dy);
#pragma unroll
                for (int q = 0; q < 4; ++q) {
                    f32x4 t = br[q];
                    t += dx * wr[0][q];
                    t += dy * wr[1][q];
                    t += dz * wr[2][q];
                    t += dv * wr[3][q];
                    t += d  * wr[4][q];
                    acc[q] += __builtin_elementwise_max(t, vzero);
                }
            }
#pragma unroll
            for (int q = 0; q < 4; ++q)
                *(f32x4*)(outb + i * OUTC + H + c0 + q * 32) = acc[q];
        }
    }
}

extern "C" void kernel_launch(void* const* d_in, const int* in_sizes, int n_in,
                              void* d_out, int out_size, void* d_ws, size_t ws_size,
                              hipStream_t stream) {
    const float* ctx    = (const float*)d_in[0];
    const float* w_prop = (const float*)d_in[1];
    const float* b_prop = (const float*)d_in[2];
    const float* w_rel  = (const float*)d_in[3];
    const float* b_rel  = (const float*)d_in[4];
    float* out = (float*)d_out;

    const int B = in_sizes[0] / (NUM_ENT * DIM_ENT);   // 16384
    const int nb = (B + BPB - 1) / BPB;                // 512 blocks
    ace_kernel<<<nb, 256, 0, stream>>>(ctx, w_prop, b_prop, w_rel, b_rel, out, B);
}